// Round 22
// baseline (94.426 us; speedup 1.0000x reference)
//
#include <hip/hip_runtime.h>
#include <math.h>

#define BATCH 16
#define CIN   3
#define HH    224
#define WW    224
#define HW    (HH*WW)
#define COUT  128
#define TAPS  147
#define CAND  192
#define TK    192

typedef __attribute__((ext_vector_type(8))) _Float16 f16x8_t;
typedef decltype(__builtin_amdgcn_cvt_pkrtz(0.f, 0.f)) f16x2_t;
typedef __attribute__((ext_vector_type(4))) float f32x4_t;
typedef __attribute__((ext_vector_type(16))) float f32x16_t;
typedef __attribute__((ext_vector_type(4))) unsigned int u32x4_t;
typedef unsigned long long u64;
typedef unsigned int u32;

// W layout (global): [g 24][129 chunks of (ch,kw)] f16x8; conv stages 12-g halves
#define B_CHUNKS   (24*129)           // global total
#define BH_CHUNKS  (12*129)           // 1548 chunks per half
#define BH_BYTES   (BH_CHUNKS*16u)    // 24768
// x copies: stride 2192 B = 548 words == 4 mod 32 -> 8-bank spread, 2-way free
#define CPY_STRIDE 2192
#define CPY_BYTES  (8*CPY_STRIDE)     // 17536
#define XFSTR     25
// conv LDS layout (3 blocks/CU): W half | xcop | xf(=lhist overlay) | lbsh | pmax
#define XCOP_OFF  BH_BYTES                      // 24768
#define XF_OFF    (XCOP_OFF + CPY_BYTES)        // 42304 (xf 6600B; lhist 4096B overlay)
#define LBSH_OFF  (XF_OFF + 6656u)              // 48960
#define PMAX_OFF  (LBSH_OFF + 512u)             // 49472
#define LDS_CONV  (PMAX_OFF + 1024u)            // 50496 -> 3 blocks/CU

// workspace layout (bytes)
#define WS_BG    0u
#define WS_BSH   (WS_BG + (unsigned)(B_CHUNKS*16))
#define WS_TOP1  (WS_BSH + 512u)
#define WS_CIDX  (WS_TOP1 + (unsigned)(BATCH*HW*4))
#define WS_CKEY  (WS_CIDX + (unsigned)(BATCH*CAND*4))
#define WS_C3V   (WS_CKEY + (unsigned)(BATCH*CAND*8))
#define WS_C3I   (WS_C3V + (unsigned)(BATCH*CAND*3*4))
#define WS_WT    (WS_C3I + (unsigned)(BATCH*CAND*3*4))
#define WS_HIST  (WS_WT + (unsigned)(TAPS*COUT*4))       // 16x1024 u32
#define ZERO_N   (BATCH*1024)

__device__ __forceinline__ void gload_lds16(const u32* g, u32* l) {
  __builtin_amdgcn_global_load_lds((const __attribute__((address_space(1))) u32*)g,
                                   (__attribute__((address_space(3))) u32*)l, 16, 0, 0);
}

// ---- prep: zero hist + fp16 folded weights + raw tap-major wT + BN shift ----
__global__ void prep_kernel(const float* __restrict__ w, const float* __restrict__ cb,
                            const float* __restrict__ gamma, const float* __restrict__ beta,
                            const float* __restrict__ mean, const float* __restrict__ var,
                            unsigned short* __restrict__ Bg, float* __restrict__ bsh,
                            float* __restrict__ wT, u32* __restrict__ gh) {
  int c = blockIdx.x;                 // 128
  int t = threadIdx.x;                // 192: g = t>>3 (0..23), kw = t&7
  int zi = c*192 + t;
  if (zi < ZERO_N) gh[zi] = 0u;
  float s = gamma[c] * (1.0f / sqrtf(var[c] + 1e-5f));
  int g = t >> 3, kw = t & 7;
  float wraw = 0.0f;
  if (g < 21 && kw < 7) {
    wraw = w[c*TAPS + g*7 + kw];
    wT[(g*7 + kw)*COUT + c] = wraw;
  }
  union { _Float16 h; unsigned short u; } cvt;
  cvt.h = (_Float16)(wraw * s);
  Bg[((g*129 + c)*8) + kw] = cvt.u;
  if (t == 0) bsh[c] = (cb[c] - mean[c]) * s + beta[c];
}

// ---- main pass: conv+BN+ReLU -> channel max + coarse hist. W in 2 LDS halves. ----
__global__ __launch_bounds__(512, 4)
void conv_mfma_kernel(const float* __restrict__ x, const unsigned short* __restrict__ Bg,
                      const float* __restrict__ bsh, float* __restrict__ top1,
                      u32* __restrict__ gh) {
  extern __shared__ char smem[];
  char* xcop  = smem + XCOP_OFF;
  float* xf   = (float*)(smem + XF_OFF);
  u32* lhist  = (u32*)(smem + XF_OFF);      // overlay: xf dead after copy-build
  float* lbsh = (float*)(smem + LBSH_OFF);
  float* pmax = (float*)(smem + PMAX_OFF);

  int tid = threadIdx.x;
  int lane = tid & 63, wv = tid >> 6;
  int p = lane & 31, kh2 = lane >> 5;
  int chp = wv & 1, pxp = wv >> 1;
  int b = blockIdx.z, w0 = blockIdx.x*16, h0 = blockIdx.y*16;
  const float* xb = x + (size_t)b * CIN * HW;
  const u32* Bg32 = (const u32*)Bg;

  // stage W half 0 (async, 1548 chunks)
#pragma unroll
  for (int k = 0; k < 4; ++k) {
    int idx = tid + k*512;
    if (idx < BH_CHUNKS) gload_lds16(Bg32 + idx*4, (u32*)smem + idx*4);
  }
  // coalesced f32 x tile: 3 x 22 rows x 24 cols, dest stride 25 (bank-spread)
  for (int i = tid; i < CIN*22*24; i += 512) {
    int cin = i / (22*24);
    int rem = i % (22*24);
    int r = rem / 24, col = rem % 24;
    int gh2 = h0 + r - 3, gw = w0 + col - 3;
    float v = 0.0f;
    if (gh2 >= 0 && gh2 < HH && gw >= 0 && gw < WW) v = xb[cin*HW + gh2*WW + gw];
    xf[(cin*22 + r)*XFSTR + col] = v;
  }
  if (tid < COUT) lbsh[tid] = bsh[tid];

  __syncthreads();   // B1: xf + W0 ready

  // build 8 shifted fp16 copies LDS->LDS
  for (int c = tid; c < 8*132; c += 512) {
    int s   = c / 132;
    int rem = c % 132;
    int cin = rem / 44;
    int rm2 = rem % 44;
    int r   = rm2 >> 1, cj = rm2 & 1;
    const float* src = xf + (cin*22 + r)*XFSTR + 8*cj + s;
    float xv[8];
#pragma unroll
    for (int j = 0; j < 8; ++j) xv[j] = src[j];
    union { f16x2_t pk[4]; u32x4_t v; } P;
#pragma unroll
    for (int j = 0; j < 4; ++j)
      P.pk[j] = __builtin_amdgcn_cvt_pkrtz(xv[2*j], xv[2*j+1]);
    *(u32x4_t*)(xcop + s*CPY_STRIDE + (cin*22 + r)*32 + cj*16) = P.v;
  }

  __syncthreads();   // B2: xcop ready, xf dead

  for (int i = tid; i < 1024; i += 512) lhist[i] = 0u;   // overlay zeroing

  f32x16_t acc[2][2];
#pragma unroll
  for (int i = 0; i < 2; ++i)
#pragma unroll
    for (int j = 0; j < 2; ++j)
#pragma unroll
      for (int r = 0; r < 16; ++r) acc[i][j][r] = 0.0f;

  const f16x8_t* B8 = (const f16x8_t*)smem;
  int lane_base = (p & 7)*CPY_STRIDE + ((p >> 3) & 1)*16;
  const char* xl = xcop + lane_base;
  int prow = p >> 4;

#pragma unroll
  for (int half = 0; half < 2; ++half) {
    if (half == 1) {
      __syncthreads();   // B3: all waves done reading W0 (lhist zero also visible)
#pragma unroll
      for (int k = 0; k < 4; ++k) {
        int idx = tid + k*512;
        if (idx < BH_CHUNKS) gload_lds16(Bg32 + (BH_CHUNKS + idx)*4, (u32*)smem + idx*4);
      }
      __syncthreads();   // B4: W1 ready
    }
#pragma unroll
    for (int kfl = 0; kfl < 6; ++kfl) {
      int glo = kfl*2 + kh2;             // local g within half
      int g = half*12 + glo;             // global g
      f16x8_t Wn[2];
#pragma unroll
      for (int i = 0; i < 2; ++i)
        Wn[i] = B8[glo*129 + chp*64 + i*32 + p];
      int cin = (g*37) >> 8;
      int kh = g - cin*7;
      int rowb = (g < 21) ? (cin*22 + kh) : 0;   // pads clamped (W=0 there)
#pragma unroll
      for (int j = 0; j < 2; ++j) {
        int pxrow = pxp*4 + j*2 + prow;
        f16x8_t Av = *(const f16x8_t*)(xl + (rowb + pxrow)*32);
#pragma unroll
        for (int i = 0; i < 2; ++i)
          acc[i][j] = __builtin_amdgcn_mfma_f32_32x32x16_f16(Wn[i], Av, acc[i][j], 0, 0, 0);
      }
    }
  }

  f32x4_t bvv[2][4];
#pragma unroll
  for (int i = 0; i < 2; ++i)
#pragma unroll
    for (int gq = 0; gq < 4; ++gq)
      bvv[i][gq] = *(const f32x4_t*)(lbsh + chp*64 + i*32 + gq*8 + kh2*4);

  float vm[2];
#pragma unroll
  for (int j = 0; j < 2; ++j) {
    float v = -1e30f;
#pragma unroll
    for (int i = 0; i < 2; ++i)
#pragma unroll
      for (int gq = 0; gq < 4; ++gq)
#pragma unroll
        for (int t = 0; t < 4; ++t)
          v = fmaxf(v, acc[i][j][gq*4 + t] + bvv[i][gq][t]);
    v = fmaxf(v, __shfl_xor(v, 32));
    vm[j] = v;
  }
  if (chp == 0 && lane < 32) {
#pragma unroll
    for (int j = 0; j < 2; ++j) pmax[pxp*64 + j*32 + p] = vm[j];
  }
  __syncthreads();
  if (chp == 1 && lane < 32) {
#pragma unroll
    for (int j = 0; j < 2; ++j) {
      int px = pxp*64 + j*32 + p;
      float r = fmaxf(fmaxf(vm[j], pmax[px]), 0.0f);
      top1[(size_t)b*HW + (h0 + (px >> 4))*WW + (w0 + (px & 15))] = r;
      atomicAdd(&lhist[__float_as_uint(r) >> 21], 1u);
    }
  }
  __syncthreads();
  for (int i = tid; i < 1024; i += 512) {
    u32 cv = lhist[i];
    if (cv) atomicAdd(&gh[b*1024 + i], cv);
  }
}

// ---- select: prebuilt hist -> scan -> (cond. fine pass) -> compact -> sort ----
#define SNT 1024
__global__ void select_kernel(const float* __restrict__ top1, const u32* __restrict__ gh,
                              int* __restrict__ cand) {
  int img = blockIdx.x, tid = threadIdx.x;   // 1024 threads
  const float* v = top1 + (size_t)img * HW;
  const float4* v4 = (const float4*)v;
  __shared__ u32 hist[1024];
  __shared__ u64 keys[1024];
  __shared__ unsigned sG, scnt, sbin, sthr, snc;

  hist[tid] = gh[img*1024 + tid];
  __syncthreads();
  if (tid < 64) {
    int j = tid;
    unsigned s = 0;
#pragma unroll
    for (int i = 0; i < 16; ++i) s += hist[j*16 + i];
    unsigned a = s;
#pragma unroll
    for (int d = 1; d < 64; d <<= 1) { unsigned t = __shfl_down(a, d); if (j + d < 64) a += t; }
    unsigned above = a - s;
    if (above < TK && a >= TK) {
      unsigned cum = above;
      for (int i = 15; i >= 0; --i) {
        unsigned c = hist[j*16 + i];
        if (cum + c >= TK) { sG = cum; scnt = c; sbin = (unsigned)(j*16 + i); break; }
        cum += c;
      }
    }
    if (j == 0 && a < TK) { sG = 0; scnt = hist[0]; sbin = 0; }
  }
  __syncthreads();
  unsigned G = sG, cnt = scnt, binT = sbin;
  unsigned thr = binT << 21;
  if (G + cnt > 1024u) {
    __syncthreads();
    hist[tid] = 0u;
    __syncthreads();
    for (int i = tid; i < HW/4; i += SNT) {
      float4 f = v4[i];
      float fv[4] = {f.x, f.y, f.z, f.w};
#pragma unroll
      for (int c = 0; c < 4; ++c) {
        unsigned ub = __float_as_uint(fv[c]);
        if ((ub >> 21) == binT) atomicAdd(&hist[(ub >> 11) & 0x3FFu], 1u);
      }
    }
    __syncthreads();
    unsigned TK2 = TK - G;
    if (tid < 64) {
      int j = tid;
      unsigned s = 0;
#pragma unroll
      for (int i = 0; i < 16; ++i) s += hist[j*16 + i];
      unsigned a = s;
#pragma unroll
      for (int d = 1; d < 64; d <<= 1) { unsigned t = __shfl_down(a, d); if (j + d < 64) a += t; }
      unsigned above = a - s;
      if (above < TK2 && a >= TK2) {
        unsigned cum = above;
        for (int i = 15; i >= 0; --i) {
          unsigned c = hist[j*16 + i];
          if (cum + c >= TK2) { sthr = (binT << 21) | ((unsigned)(j*16 + i) << 11); break; }
          cum += c;
        }
      }
      if (j == 0 && a < TK2) sthr = binT << 21;
    }
    __syncthreads();
    thr = sthr;
  }
  if (tid == 0) snc = 0u;
  keys[tid] = 0ull;
  __syncthreads();
  for (int i = tid; i < HW/4; i += SNT) {
    float4 f = v4[i];
    float fv[4] = {f.x, f.y, f.z, f.w};
#pragma unroll
    for (int c = 0; c < 4; ++c) {
      unsigned ub = __float_as_uint(fv[c]);
      if (ub >= thr) {
        unsigned pp = atomicAdd(&snc, 1u);
        if (pp < 1024u) keys[pp] = ((u64)ub << 32) | (unsigned)(~(unsigned)(4*i + c));
      }
    }
  }
  for (unsigned kk = 2; kk <= 1024; kk <<= 1)
    for (unsigned j = kk >> 1; j > 0; j >>= 1) {
      __syncthreads();
      unsigned t = tid, ixj = t ^ j;
      if (ixj > t) {
        u64 a = keys[t], b = keys[ixj];
        bool desc = ((t & kk) == 0);
        if ((a < b) == desc) { keys[t] = b; keys[ixj] = a; }
      }
    }
  __syncthreads();
  if (tid < CAND) {
    u64 key = keys[tid];
    cand[img*CAND + tid] = (key == 0ull) ? -1 : (int)(~(unsigned)(key & 0xFFFFFFFFull));
  }
}

// ---- fp64 recompute at candidates (coalesced wT, LDS x-patch, parallel top3) ----
__global__ void refine_kernel(const float* __restrict__ x, const float* __restrict__ wT,
                              const float* __restrict__ cb, const float* __restrict__ gamma,
                              const float* __restrict__ beta, const float* __restrict__ mean,
                              const float* __restrict__ var, const int* __restrict__ cand,
                              u64* __restrict__ ckey,
                              float* __restrict__ c3v, float* __restrict__ c3i) {
#pragma clang fp contract(off)
  int slot = blockIdx.x, img = blockIdx.y;
  int c = threadIdx.x;                       // 128 threads = channels
  int sidx = cand[img*CAND + slot];
  if (sidx < 0) {
    if (c == 0) {
      ckey[img*CAND + slot] = 0ull;
      for (int j = 0; j < 3; ++j) { c3v[(img*CAND+slot)*3+j] = 0.f; c3i[(img*CAND+slot)*3+j] = 0.f; }
    }
    return;
  }
  int h = sidx / WW, wq = sidx % WW;
  const float* xb = x + (size_t)img * CIN * HW;

  __shared__ float xs[TAPS + 13];
  for (int t = c; t < TAPS; t += 128) {
    int cin = t / 49, r = t % 49;
    int kh = r / 7, kw = r % 7;
    int gh = h - 3 + kh, gw = wq - 3 + kw;
    float v = 0.0f;
    if (gh >= 0 && gh < HH && gw >= 0 && gw < WW) v = xb[cin*HW + gh*WW + gw];
    xs[t] = v;
  }
  __syncthreads();

  double acc = 0.0;
#pragma unroll 7
  for (int t = 0; t < TAPS; ++t)
    acc = fma((double)xs[t], (double)wT[t*COUT + c], acc);

  float y = (float)acc;
  y = y + cb[c];
  float s  = gamma[c] * (1.0f / sqrtf(var[c] + 1e-5f));
  float t1 = (y - mean[c]) * s;
  float z  = t1 + beta[c];
  z = fmaxf(z, 0.0f);

  __shared__ u64 zk[COUT];
  zk[c] = ((u64)__float_as_uint(z) << 32) | (unsigned)(127 - c);
  __syncthreads();
  if (c < 64) {
    u64 k0 = zk[c], k1 = zk[c + 64];
    int base = (img*CAND + slot)*3;
#pragma unroll
    for (int pick = 0; pick < 3; ++pick) {
      u64 m = (k0 > k1) ? k0 : k1;
#pragma unroll
      for (int d = 1; d < 64; d <<= 1) {
        u64 o = __shfl_xor((unsigned long long)m, d);
        if (o > m) m = o;
      }
      if (c == 0) {
        c3v[base + pick] = __uint_as_float((unsigned)(m >> 32));
        c3i[base + pick] = (float)(127 - (int)(m & 0xFFFFFFFFull));
        if (pick == 0)
          ckey[img*CAND + slot] = ((u64)(m >> 32) << 32) | (unsigned)(~(unsigned)sidx);
      }
      if (k0 == m) k0 = 0ull;
      if (k1 == m) k1 = 0ull;
    }
  }
}

// ---- final: sort 192 refined candidates, write all three outputs ----
__global__ void final_kernel(const u64* __restrict__ ckey, const int* __restrict__ cand,
                             const float* __restrict__ c3v, const float* __restrict__ c3i,
                             float* __restrict__ out) {
  int img = blockIdx.x, tid = threadIdx.x;   // 256 threads
  __shared__ u64 k[256];
  __shared__ int pay[256];
  k[tid]  = (tid < CAND) ? ckey[img*CAND + tid] : 0ull;
  pay[tid] = tid;
  for (unsigned kk = 2; kk <= 256; kk <<= 1)
    for (unsigned j = kk >> 1; j > 0; j >>= 1) {
      __syncthreads();
      unsigned i = tid, ixj = i ^ j;
      if (ixj > i) {
        u64 a = k[i], b = k[ixj];
        bool desc = ((i & kk) == 0);
        if ((a < b) == desc) {
          k[i] = b; k[ixj] = a;
          int p = pay[i]; pay[i] = pay[ixj]; pay[ixj] = p;
        }
      }
    }
  __syncthreads();
  if (tid < 128) {
    int slot = pay[tid];
    int sidx = cand[img*CAND + slot];
    out[12288 + img*128 + tid] = (float)sidx;
    int base = (img*CAND + slot)*3;
    for (int j = 0; j < 3; ++j) {
      out[(img*3 + j)*128 + tid]        = c3i[base + j];
      out[6144 + (img*3 + j)*128 + tid] = c3v[base + j];
    }
  }
}

extern "C" void kernel_launch(void* const* d_in, const int* in_sizes, int n_in,
                              void* d_out, int out_size, void* d_ws, size_t ws_size,
                              hipStream_t stream) {
  const float* x     = (const float*)d_in[0];
  const float* w     = (const float*)d_in[1];
  const float* cb    = (const float*)d_in[2];
  const float* gamma = (const float*)d_in[3];
  const float* beta  = (const float*)d_in[4];
  const float* mean  = (const float*)d_in[5];
  const float* var   = (const float*)d_in[6];
  float* out = (float*)d_out;
  char*  ws  = (char*)d_ws;

  unsigned short* Bg = (unsigned short*)(ws + WS_BG);
  float* bsh  = (float*)(ws + WS_BSH);
  float* top1 = (float*)(ws + WS_TOP1);
  int*   cidx = (int*)(ws + WS_CIDX);
  u64*   ck   = (u64*)(ws + WS_CKEY);
  float* c3v = (float*)(ws + WS_C3V);
  float* c3i = (float*)(ws + WS_C3I);
  float* wT  = (float*)(ws + WS_WT);
  u32* gh    = (u32*)(ws + WS_HIST);

  prep_kernel<<<COUT, 192, 0, stream>>>(w, cb, gamma, beta, mean, var, Bg, bsh, wT, gh);
  conv_mfma_kernel<<<dim3(WW/16, HH/16, BATCH), 512, LDS_CONV, stream>>>(x, Bg, bsh, top1, gh);
  select_kernel<<<BATCH, SNT, 0, stream>>>(top1, gh, cidx);
  refine_kernel<<<dim3(CAND, BATCH), COUT, 0, stream>>>(x, wT, cb, gamma, beta, mean, var,
                                                        cidx, ck, c3v, c3i);
  final_kernel<<<BATCH, 256, 0, stream>>>(ck, cidx, c3v, c3i, out);
}

// Round 23
// 94.140 us; speedup vs baseline: 1.0030x; 1.0030x over previous
//
#include <hip/hip_runtime.h>
#include <math.h>

#define BATCH 16
#define CIN   3
#define HH    224
#define WW    224
#define HW    (HH*WW)
#define COUT  128
#define TAPS  147
#define CAND  192
#define TK    192

typedef __attribute__((ext_vector_type(8))) _Float16 f16x8_t;
typedef decltype(__builtin_amdgcn_cvt_pkrtz(0.f, 0.f)) f16x2_t;
typedef __attribute__((ext_vector_type(4))) float f32x4_t;
typedef __attribute__((ext_vector_type(16))) float f32x16_t;
typedef __attribute__((ext_vector_type(4))) unsigned int u32x4_t;
typedef unsigned long long u64;
typedef unsigned int u32;

// W layout: [g 24][129 chunks of (ch,kw)] f16x8 chunks (LDS, bank-skewed)
#define B_CHUNKS  (24*129)
#define B_BYTES   (B_CHUNKS*16u)      // 49536
// x copies: stride 2192 B = 548 words == 4 mod 32 -> 8-bank spread, 2-way free
#define CPY_STRIDE 2192
#define CPY_BYTES  (8*CPY_STRIDE)     // 17536
// f32 staging tile: row stride 25 words (coprime 32 -> conflict-free copy-build reads)
#define XFSTR     25
// conv LDS layout
#define XF_OFF    (B_BYTES + CPY_BYTES)        // 67072
#define LBSH_OFF  (XF_OFF + 6656u)             // 73728 (xf 3*22*25*4=6600, pad 6656)
#define PMAX_OFF  (LBSH_OFF + 512u)            // 74240
#define LHIST_OFF (PMAX_OFF + 1024u)           // 75264
#define LDS_CONV  (LHIST_OFF + 4096u)          // 79360 -> 2 blocks/CU

// workspace layout (bytes)
#define WS_BG    0u
#define WS_BSH   (WS_BG + B_BYTES)
#define WS_TOP1  (WS_BSH + 512u)
#define WS_CIDX  (WS_TOP1 + (unsigned)(BATCH*HW*4))
#define WS_CKEY  (WS_CIDX + (unsigned)(BATCH*CAND*4))
#define WS_C3V   (WS_CKEY + (unsigned)(BATCH*CAND*8))
#define WS_C3I   (WS_C3V + (unsigned)(BATCH*CAND*3*4))
#define WS_WT    (WS_C3I + (unsigned)(BATCH*CAND*3*4))
#define WS_HIST  (WS_WT + (unsigned)(TAPS*COUT*4))       // 16x1024 u32
#define ZERO_N   (BATCH*1024)

__device__ __forceinline__ void gload_lds16(const u32* g, u32* l) {
  __builtin_amdgcn_global_load_lds((const __attribute__((address_space(1))) u32*)g,
                                   (__attribute__((address_space(3))) u32*)l, 16, 0, 0);
}

// ---- prep: zero hist + fp16 folded weights + raw tap-major wT + BN shift ----
__global__ void prep_kernel(const float* __restrict__ w, const float* __restrict__ cb,
                            const float* __restrict__ gamma, const float* __restrict__ beta,
                            const float* __restrict__ mean, const float* __restrict__ var,
                            unsigned short* __restrict__ Bg, float* __restrict__ bsh,
                            float* __restrict__ wT, u32* __restrict__ gh) {
  int c = blockIdx.x;                 // 128
  int t = threadIdx.x;                // 192: g = t>>3 (0..23), kw = t&7
  int zi = c*192 + t;
  if (zi < ZERO_N) gh[zi] = 0u;
  float s = gamma[c] * (1.0f / sqrtf(var[c] + 1e-5f));
  int g = t >> 3, kw = t & 7;
  float wraw = 0.0f;
  if (g < 21 && kw < 7) {
    wraw = w[c*TAPS + g*7 + kw];
    wT[(g*7 + kw)*COUT + c] = wraw;
  }
  union { _Float16 h; unsigned short u; } cvt;
  cvt.h = (_Float16)(wraw * s);
  Bg[((g*129 + c)*8) + kw] = cvt.u;
  if (t == 0) bsh[c] = (cb[c] - mean[c]) * s + beta[c];
}

// ---- main pass: conv+BN+ReLU -> channel max + coarse hist ----
__global__ __launch_bounds__(512, 4)
void conv_mfma_kernel(const float* __restrict__ x, const unsigned short* __restrict__ Bg,
                      const float* __restrict__ bsh, float* __restrict__ top1,
                      u32* __restrict__ gh) {
  extern __shared__ char smem[];
  char* xcop = smem + B_BYTES;
  float* xf   = (float*)(smem + XF_OFF);
  float* lbsh = (float*)(smem + LBSH_OFF);
  float* pmax = (float*)(smem + PMAX_OFF);
  u32* lhist  = (u32*)(smem + LHIST_OFF);

  int tid = threadIdx.x;
  int lane = tid & 63, wv = tid >> 6;
  int p = lane & 31, kh2 = lane >> 5;
  int chp = wv & 1, pxp = wv >> 1;
  int b = blockIdx.z, w0 = blockIdx.x*16, h0 = blockIdx.y*16;
  const float* xb = x + (size_t)b * CIN * HW;
  const u32* Bg32 = (const u32*)Bg;

  // stage W (async, 16B chunks)
#pragma unroll
  for (int k = 0; k < 7; ++k) {
    int idx = tid + k*512;
    if (idx < B_CHUNKS) gload_lds16(Bg32 + idx*4, (u32*)smem + idx*4);
  }
  // coalesced f32 x tile: 3 x 22 rows x 24 cols, dest stride 25 (bank-spread)
  for (int i = tid; i < CIN*22*24; i += 512) {
    int cin = i / (22*24);
    int rem = i % (22*24);
    int r = rem / 24, col = rem % 24;
    int gh2 = h0 + r - 3, gw = w0 + col - 3;
    float v = 0.0f;
    if (gh2 >= 0 && gh2 < HH && gw >= 0 && gw < WW) v = xb[cin*HW + gh2*WW + gw];
    xf[(cin*22 + r)*XFSTR + col] = v;
  }
  if (tid < COUT) lbsh[tid] = bsh[tid];
  for (int i = tid; i < 1024; i += 512) lhist[i] = 0u;

  __syncthreads();   // xf visible (W async loads also drained)

  // build 8 shifted fp16 copies LDS->LDS (no TA traffic, conflict-free reads)
  for (int c = tid; c < 8*132; c += 512) {
    int s   = c / 132;
    int rem = c % 132;
    int cin = rem / 44;
    int rm2 = rem % 44;
    int r   = rm2 >> 1, cj = rm2 & 1;
    const float* src = xf + (cin*22 + r)*XFSTR + 8*cj + s;   // max col 8+7+7=22 < 24
    float xv[8];
#pragma unroll
    for (int j = 0; j < 8; ++j) xv[j] = src[j];
    union { f16x2_t pk[4]; u32x4_t v; } P;
#pragma unroll
    for (int j = 0; j < 4; ++j)
      P.pk[j] = __builtin_amdgcn_cvt_pkrtz(xv[2*j], xv[2*j+1]);
    *(u32x4_t*)(xcop + s*CPY_STRIDE + (cin*22 + r)*32 + cj*16) = P.v;
  }

  __syncthreads();   // xcop ready

  f32x16_t acc[2][2];
#pragma unroll
  for (int i = 0; i < 2; ++i)
#pragma unroll
    for (int j = 0; j < 2; ++j)
#pragma unroll
      for (int r = 0; r < 16; ++r) acc[i][j][r] = 0.0f;

  const f16x8_t* B8 = (const f16x8_t*)smem;
  int lane_base = (p & 7)*CPY_STRIDE + ((p >> 3) & 1)*16;
  const char* xl = xcop + lane_base;
  int prow = p >> 4;

#pragma unroll
  for (int kf = 0; kf < 12; ++kf) {
    int g = kf*2 + kh2;
    f16x8_t Wn[2];
#pragma unroll
    for (int i = 0; i < 2; ++i)
      Wn[i] = B8[g*129 + chp*64 + i*32 + p];
    int cin = (g*37) >> 8;
    int kh = g - cin*7;
    int rowb = (g < 21) ? (cin*22 + kh) : 0;
#pragma unroll
    for (int j = 0; j < 2; ++j) {
      int pxrow = pxp*4 + j*2 + prow;
      f16x8_t Av = *(const f16x8_t*)(xl + (rowb + pxrow)*32);
#pragma unroll
      for (int i = 0; i < 2; ++i)
        acc[i][j] = __builtin_amdgcn_mfma_f32_32x32x16_f16(Wn[i], Av, acc[i][j], 0, 0, 0);
    }
  }

  f32x4_t bvv[2][4];
#pragma unroll
  for (int i = 0; i < 2; ++i)
#pragma unroll
    for (int gq = 0; gq < 4; ++gq)
      bvv[i][gq] = *(const f32x4_t*)(lbsh + chp*64 + i*32 + gq*8 + kh2*4);

  float vm[2];
#pragma unroll
  for (int j = 0; j < 2; ++j) {
    float v = -1e30f;
#pragma unroll
    for (int i = 0; i < 2; ++i)
#pragma unroll
      for (int gq = 0; gq < 4; ++gq)
#pragma unroll
        for (int t = 0; t < 4; ++t)
          v = fmaxf(v, acc[i][j][gq*4 + t] + bvv[i][gq][t]);
    v = fmaxf(v, __shfl_xor(v, 32));
    vm[j] = v;
  }
  if (chp == 0 && lane < 32) {
#pragma unroll
    for (int j = 0; j < 2; ++j) pmax[pxp*64 + j*32 + p] = vm[j];
  }
  __syncthreads();
  if (chp == 1 && lane < 32) {
#pragma unroll
    for (int j = 0; j < 2; ++j) {
      int px = pxp*64 + j*32 + p;
      float r = fmaxf(fmaxf(vm[j], pmax[px]), 0.0f);
      top1[(size_t)b*HW + (h0 + (px >> 4))*WW + (w0 + (px & 15))] = r;
      atomicAdd(&lhist[__float_as_uint(r) >> 21], 1u);
    }
  }
  __syncthreads();
  for (int i = tid; i < 1024; i += 512) {
    u32 cv = lhist[i];
    if (cv) atomicAdd(&gh[b*1024 + i], cv);
  }
}

// ---- select: prebuilt hist -> scan -> (cond. fine pass) -> compact -> sort ----
#define SNT 1024
__global__ void select_kernel(const float* __restrict__ top1, const u32* __restrict__ gh,
                              int* __restrict__ cand) {
  int img = blockIdx.x, tid = threadIdx.x;   // 1024 threads
  const float* v = top1 + (size_t)img * HW;
  const float4* v4 = (const float4*)v;
  __shared__ u32 hist[1024];
  __shared__ u64 keys[1024];
  __shared__ unsigned sG, scnt, sbin, sthr, snc;

  hist[tid] = gh[img*1024 + tid];
  __syncthreads();
  if (tid < 64) {
    int j = tid;
    unsigned s = 0;
#pragma unroll
    for (int i = 0; i < 16; ++i) s += hist[j*16 + i];
    unsigned a = s;
#pragma unroll
    for (int d = 1; d < 64; d <<= 1) { unsigned t = __shfl_down(a, d); if (j + d < 64) a += t; }
    unsigned above = a - s;
    if (above < TK && a >= TK) {
      unsigned cum = above;
      for (int i = 15; i >= 0; --i) {
        unsigned c = hist[j*16 + i];
        if (cum + c >= TK) { sG = cum; scnt = c; sbin = (unsigned)(j*16 + i); break; }
        cum += c;
      }
    }
    if (j == 0 && a < TK) { sG = 0; scnt = hist[0]; sbin = 0; }
  }
  __syncthreads();
  unsigned G = sG, cnt = scnt, binT = sbin;
  unsigned thr = binT << 21;
  if (G + cnt > 1024u) {
    __syncthreads();
    hist[tid] = 0u;
    __syncthreads();
    for (int i = tid; i < HW/4; i += SNT) {
      float4 f = v4[i];
      float fv[4] = {f.x, f.y, f.z, f.w};
#pragma unroll
      for (int c = 0; c < 4; ++c) {
        unsigned ub = __float_as_uint(fv[c]);
        if ((ub >> 21) == binT) atomicAdd(&hist[(ub >> 11) & 0x3FFu], 1u);
      }
    }
    __syncthreads();
    unsigned TK2 = TK - G;
    if (tid < 64) {
      int j = tid;
      unsigned s = 0;
#pragma unroll
      for (int i = 0; i < 16; ++i) s += hist[j*16 + i];
      unsigned a = s;
#pragma unroll
      for (int d = 1; d < 64; d <<= 1) { unsigned t = __shfl_down(a, d); if (j + d < 64) a += t; }
      unsigned above = a - s;
      if (above < TK2 && a >= TK2) {
        unsigned cum = above;
        for (int i = 15; i >= 0; --i) {
          unsigned c = hist[j*16 + i];
          if (cum + c >= TK2) { sthr = (binT << 21) | ((unsigned)(j*16 + i) << 11); break; }
          cum += c;
        }
      }
      if (j == 0 && a < TK2) sthr = binT << 21;
    }
    __syncthreads();
    thr = sthr;
  }
  if (tid == 0) snc = 0u;
  keys[tid] = 0ull;
  __syncthreads();
  for (int i = tid; i < HW/4; i += SNT) {
    float4 f = v4[i];
    float fv[4] = {f.x, f.y, f.z, f.w};
#pragma unroll
    for (int c = 0; c < 4; ++c) {
      unsigned ub = __float_as_uint(fv[c]);
      if (ub >= thr) {
        unsigned pp = atomicAdd(&snc, 1u);
        if (pp < 1024u) keys[pp] = ((u64)ub << 32) | (unsigned)(~(unsigned)(4*i + c));
      }
    }
  }
  for (unsigned kk = 2; kk <= 1024; kk <<= 1)
    for (unsigned j = kk >> 1; j > 0; j >>= 1) {
      __syncthreads();
      unsigned t = tid, ixj = t ^ j;
      if (ixj > t) {
        u64 a = keys[t], b = keys[ixj];
        bool desc = ((t & kk) == 0);
        if ((a < b) == desc) { keys[t] = b; keys[ixj] = a; }
      }
    }
  __syncthreads();
  if (tid < CAND) {
    u64 key = keys[tid];
    cand[img*CAND + tid] = (key == 0ull) ? -1 : (int)(~(unsigned)(key & 0xFFFFFFFFull));
  }
}

// ---- fp64 recompute at candidates (coalesced wT, LDS x-patch, parallel top3) ----
__global__ void refine_kernel(const float* __restrict__ x, const float* __restrict__ wT,
                              const float* __restrict__ cb, const float* __restrict__ gamma,
                              const float* __restrict__ beta, const float* __restrict__ mean,
                              const float* __restrict__ var, const int* __restrict__ cand,
                              u64* __restrict__ ckey,
                              float* __restrict__ c3v, float* __restrict__ c3i) {
#pragma clang fp contract(off)
  int slot = blockIdx.x, img = blockIdx.y;
  int c = threadIdx.x;                       // 128 threads = channels
  int sidx = cand[img*CAND + slot];
  if (sidx < 0) {
    if (c == 0) {
      ckey[img*CAND + slot] = 0ull;
      for (int j = 0; j < 3; ++j) { c3v[(img*CAND+slot)*3+j] = 0.f; c3i[(img*CAND+slot)*3+j] = 0.f; }
    }
    return;
  }
  int h = sidx / WW, wq = sidx % WW;
  const float* xb = x + (size_t)img * CIN * HW;

  __shared__ float xs[TAPS + 13];
  for (int t = c; t < TAPS; t += 128) {
    int cin = t / 49, r = t % 49;
    int kh = r / 7, kw = r % 7;
    int gh = h - 3 + kh, gw = wq - 3 + kw;
    float v = 0.0f;
    if (gh >= 0 && gh < HH && gw >= 0 && gw < WW) v = xb[cin*HW + gh*WW + gw];
    xs[t] = v;
  }
  __syncthreads();

  double acc = 0.0;
#pragma unroll 7
  for (int t = 0; t < TAPS; ++t)
    acc = fma((double)xs[t], (double)wT[t*COUT + c], acc);

  float y = (float)acc;
  y = y + cb[c];
  float s  = gamma[c] * (1.0f / sqrtf(var[c] + 1e-5f));
  float t1 = (y - mean[c]) * s;
  float z  = t1 + beta[c];
  z = fmaxf(z, 0.0f);

  __shared__ u64 zk[COUT];
  zk[c] = ((u64)__float_as_uint(z) << 32) | (unsigned)(127 - c);
  __syncthreads();
  if (c < 64) {
    u64 k0 = zk[c], k1 = zk[c + 64];
    int base = (img*CAND + slot)*3;
#pragma unroll
    for (int pick = 0; pick < 3; ++pick) {
      u64 m = (k0 > k1) ? k0 : k1;
#pragma unroll
      for (int d = 1; d < 64; d <<= 1) {
        u64 o = __shfl_xor((unsigned long long)m, d);
        if (o > m) m = o;
      }
      if (c == 0) {
        c3v[base + pick] = __uint_as_float((unsigned)(m >> 32));
        c3i[base + pick] = (float)(127 - (int)(m & 0xFFFFFFFFull));
        if (pick == 0)
          ckey[img*CAND + slot] = ((u64)(m >> 32) << 32) | (unsigned)(~(unsigned)sidx);
      }
      if (k0 == m) k0 = 0ull;
      if (k1 == m) k1 = 0ull;
    }
  }
}

// ---- final: sort 192 refined candidates, write all three outputs ----
__global__ void final_kernel(const u64* __restrict__ ckey, const int* __restrict__ cand,
                             const float* __restrict__ c3v, const float* __restrict__ c3i,
                             float* __restrict__ out) {
  int img = blockIdx.x, tid = threadIdx.x;   // 256 threads
  __shared__ u64 k[256];
  __shared__ int pay[256];
  k[tid]  = (tid < CAND) ? ckey[img*CAND + tid] : 0ull;
  pay[tid] = tid;
  for (unsigned kk = 2; kk <= 256; kk <<= 1)
    for (unsigned j = kk >> 1; j > 0; j >>= 1) {
      __syncthreads();
      unsigned i = tid, ixj = i ^ j;
      if (ixj > i) {
        u64 a = k[i], b = k[ixj];
        bool desc = ((i & kk) == 0);
        if ((a < b) == desc) {
          k[i] = b; k[ixj] = a;
          int p = pay[i]; pay[i] = pay[ixj]; pay[ixj] = p;
        }
      }
    }
  __syncthreads();
  if (tid < 128) {
    int slot = pay[tid];
    int sidx = cand[img*CAND + slot];
    out[12288 + img*128 + tid] = (float)sidx;
    int base = (img*CAND + slot)*3;
    for (int j = 0; j < 3; ++j) {
      out[(img*3 + j)*128 + tid]        = c3i[base + j];
      out[6144 + (img*3 + j)*128 + tid] = c3v[base + j];
    }
  }
}

extern "C" void kernel_launch(void* const* d_in, const int* in_sizes, int n_in,
                              void* d_out, int out_size, void* d_ws, size_t ws_size,
                              hipStream_t stream) {
  const float* x     = (const float*)d_in[0];
  const float* w     = (const float*)d_in[1];
  const float* cb    = (const float*)d_in[2];
  const float* gamma = (const float*)d_in[3];
  const float* beta  = (const float*)d_in[4];
  const float* mean  = (const float*)d_in[5];
  const float* var   = (const float*)d_in[6];
  float* out = (float*)d_out;
  char*  ws  = (char*)d_ws;

  unsigned short* Bg = (unsigned short*)(ws + WS_BG);
  float* bsh  = (float*)(ws + WS_BSH);
  float* top1 = (float*)(ws + WS_TOP1);
  int*   cidx = (int*)(ws + WS_CIDX);
  u64*   ck   = (u64*)(ws + WS_CKEY);
  float* c3v = (float*)(ws + WS_C3V);
  float* c3i = (float*)(ws + WS_C3I);
  float* wT  = (float*)(ws + WS_WT);
  u32* gh    = (u32*)(ws + WS_HIST);

  prep_kernel<<<COUT, 192, 0, stream>>>(w, cb, gamma, beta, mean, var, Bg, bsh, wT, gh);
  conv_mfma_kernel<<<dim3(WW/16, HH/16, BATCH), 512, LDS_CONV, stream>>>(x, Bg, bsh, top1, gh);
  select_kernel<<<BATCH, SNT, 0, stream>>>(top1, gh, cidx);
  refine_kernel<<<dim3(CAND, BATCH), COUT, 0, stream>>>(x, wT, cb, gamma, beta, mean, var,
                                                        cidx, ck, c3v, c3i);
  final_kernel<<<BATCH, 256, 0, stream>>>(ck, cidx, c3v, c3i, out);
}

// Round 24
// 92.146 us; speedup vs baseline: 1.0247x; 1.0216x over previous
//
#include <hip/hip_runtime.h>
#include <math.h>

#define BATCH 16
#define CIN   3
#define HH    224
#define WW    224
#define HW    (HH*WW)
#define COUT  128
#define TAPS  147
#define CAND  192
#define TK    192

typedef __attribute__((ext_vector_type(8))) _Float16 f16x8_t;
typedef decltype(__builtin_amdgcn_cvt_pkrtz(0.f, 0.f)) f16x2_t;
typedef __attribute__((ext_vector_type(4))) float f32x4_t;
typedef __attribute__((ext_vector_type(16))) float f32x16_t;
typedef __attribute__((ext_vector_type(4))) unsigned int u32x4_t;
typedef unsigned long long u64;
typedef unsigned int u32;

// W layout (global): [g 24][129 chunks of (ch,kw)] f16x8. Conv stages only g=0..21
// (g=22,23 are all-zero pad octets -> dead K, not staged, not computed).
#define BSTG_CHUNKS (22*129)          // 2838 staged chunks
#define B_BYTES     (BSTG_CHUNKS*16u) // 45408
// x copies: stride 2192 B = 548 words == 4 mod 32 -> 8-bank spread, 2-way free
#define CPY_STRIDE 2192
#define CPY_BYTES  (8*CPY_STRIDE)     // 17536
// f32 staging tile: row stride 25 words (coprime 32 -> conflict-free copy-build reads)
#define XFSTR     25
// conv LDS layout
#define XF_OFF    (B_BYTES + CPY_BYTES)        // 62944
#define LBSH_OFF  (XF_OFF + 6656u)             // 69600 (xf 3*22*25*4=6600, pad 6656)
#define PMAX_OFF  (LBSH_OFF + 512u)            // 70112
#define LHIST_OFF (PMAX_OFF + 1024u)           // 71136
#define LDS_CONV  (LHIST_OFF + 4096u)          // 75232 -> 2 blocks/CU

// workspace layout (bytes); Bg buffer holds full 24-g table (prep writes all)
#define WS_BG    0u
#define WS_BSH   (WS_BG + (unsigned)(24*129*16))
#define WS_TOP1  (WS_BSH + 512u)
#define WS_CIDX  (WS_TOP1 + (unsigned)(BATCH*HW*4))
#define WS_CKEY  (WS_CIDX + (unsigned)(BATCH*CAND*4))
#define WS_C3V   (WS_CKEY + (unsigned)(BATCH*CAND*8))
#define WS_C3I   (WS_C3V + (unsigned)(BATCH*CAND*3*4))
#define WS_WT    (WS_C3I + (unsigned)(BATCH*CAND*3*4))
#define WS_HIST  (WS_WT + (unsigned)(TAPS*COUT*4))       // 16x1024 u32
#define ZERO_N   (BATCH*1024)

__device__ __forceinline__ void gload_lds16(const u32* g, u32* l) {
  __builtin_amdgcn_global_load_lds((const __attribute__((address_space(1))) u32*)g,
                                   (__attribute__((address_space(3))) u32*)l, 16, 0, 0);
}

// ---- prep: zero hist + fp16 folded weights + raw tap-major wT + BN shift ----
__global__ void prep_kernel(const float* __restrict__ w, const float* __restrict__ cb,
                            const float* __restrict__ gamma, const float* __restrict__ beta,
                            const float* __restrict__ mean, const float* __restrict__ var,
                            unsigned short* __restrict__ Bg, float* __restrict__ bsh,
                            float* __restrict__ wT, u32* __restrict__ gh) {
  int c = blockIdx.x;                 // 128
  int t = threadIdx.x;                // 192: g = t>>3 (0..23), kw = t&7
  int zi = c*192 + t;
  if (zi < ZERO_N) gh[zi] = 0u;
  float s = gamma[c] * (1.0f / sqrtf(var[c] + 1e-5f));
  int g = t >> 3, kw = t & 7;
  float wraw = 0.0f;
  if (g < 21 && kw < 7) {
    wraw = w[c*TAPS + g*7 + kw];
    wT[(g*7 + kw)*COUT + c] = wraw;
  }
  union { _Float16 h; unsigned short u; } cvt;
  cvt.h = (_Float16)(wraw * s);
  Bg[((g*129 + c)*8) + kw] = cvt.u;
  if (t == 0) bsh[c] = (cb[c] - mean[c]) * s + beta[c];
}

// ---- main pass: conv+BN+ReLU -> channel max + coarse hist (11 K-iterations) ----
__global__ __launch_bounds__(512, 4)
void conv_mfma_kernel(const float* __restrict__ x, const unsigned short* __restrict__ Bg,
                      const float* __restrict__ bsh, float* __restrict__ top1,
                      u32* __restrict__ gh) {
  extern __shared__ char smem[];
  char* xcop = smem + B_BYTES;
  float* xf   = (float*)(smem + XF_OFF);
  float* lbsh = (float*)(smem + LBSH_OFF);
  float* pmax = (float*)(smem + PMAX_OFF);
  u32* lhist  = (u32*)(smem + LHIST_OFF);

  int tid = threadIdx.x;
  int lane = tid & 63, wv = tid >> 6;
  int p = lane & 31, kh2 = lane >> 5;
  int chp = wv & 1, pxp = wv >> 1;
  int b = blockIdx.z, w0 = blockIdx.x*16, h0 = blockIdx.y*16;
  const float* xb = x + (size_t)b * CIN * HW;
  const u32* Bg32 = (const u32*)Bg;

  // stage W g=0..21 (async, 2838 chunks)
#pragma unroll
  for (int k = 0; k < 6; ++k) {
    int idx = tid + k*512;
    if (idx < BSTG_CHUNKS) gload_lds16(Bg32 + idx*4, (u32*)smem + idx*4);
  }
  // coalesced f32 x tile: 3 x 22 rows x 24 cols, dest stride 25 (bank-spread)
  for (int i = tid; i < CIN*22*24; i += 512) {
    int cin = i / (22*24);
    int rem = i % (22*24);
    int r = rem / 24, col = rem % 24;
    int gh2 = h0 + r - 3, gw = w0 + col - 3;
    float v = 0.0f;
    if (gh2 >= 0 && gh2 < HH && gw >= 0 && gw < WW) v = xb[cin*HW + gh2*WW + gw];
    xf[(cin*22 + r)*XFSTR + col] = v;
  }
  if (tid < COUT) lbsh[tid] = bsh[tid];
  for (int i = tid; i < 1024; i += 512) lhist[i] = 0u;

  __syncthreads();   // xf visible (W async loads also drained)

  // build 8 shifted fp16 copies LDS->LDS (no TA traffic, conflict-free reads)
  for (int c = tid; c < 8*132; c += 512) {
    int s   = c / 132;
    int rem = c % 132;
    int cin = rem / 44;
    int rm2 = rem % 44;
    int r   = rm2 >> 1, cj = rm2 & 1;
    const float* src = xf + (cin*22 + r)*XFSTR + 8*cj + s;   // max col 8+7+7=22 < 24
    float xv[8];
#pragma unroll
    for (int j = 0; j < 8; ++j) xv[j] = src[j];
    union { f16x2_t pk[4]; u32x4_t v; } P;
#pragma unroll
    for (int j = 0; j < 4; ++j)
      P.pk[j] = __builtin_amdgcn_cvt_pkrtz(xv[2*j], xv[2*j+1]);
    *(u32x4_t*)(xcop + s*CPY_STRIDE + (cin*22 + r)*32 + cj*16) = P.v;
  }

  __syncthreads();   // xcop ready

  f32x16_t acc[2][2];
#pragma unroll
  for (int i = 0; i < 2; ++i)
#pragma unroll
    for (int j = 0; j < 2; ++j)
#pragma unroll
      for (int r = 0; r < 16; ++r) acc[i][j][r] = 0.0f;

  const f16x8_t* B8 = (const f16x8_t*)smem;
  int lane_base = (p & 7)*CPY_STRIDE + ((p >> 3) & 1)*16;
  const char* xl = xcop + lane_base;
  int prow = p >> 4;

  // 11 K-iterations cover g=0..21 (g=21 is the single zero-pad octet)
#pragma unroll
  for (int kf = 0; kf < 11; ++kf) {
    int g = kf*2 + kh2;
    f16x8_t Wn[2];
#pragma unroll
    for (int i = 0; i < 2; ++i)
      Wn[i] = B8[g*129 + chp*64 + i*32 + p];
    int cin = (g*37) >> 8;
    int kh = g - cin*7;
    int rowb = (g < 21) ? (cin*22 + kh) : 0;   // g=21 clamped (W=0 there)
#pragma unroll
    for (int j = 0; j < 2; ++j) {
      int pxrow = pxp*4 + j*2 + prow;
      f16x8_t Av = *(const f16x8_t*)(xl + (rowb + pxrow)*32);
#pragma unroll
      for (int i = 0; i < 2; ++i)
        acc[i][j] = __builtin_amdgcn_mfma_f32_32x32x16_f16(Wn[i], Av, acc[i][j], 0, 0, 0);
    }
  }

  f32x4_t bvv[2][4];
#pragma unroll
  for (int i = 0; i < 2; ++i)
#pragma unroll
    for (int gq = 0; gq < 4; ++gq)
      bvv[i][gq] = *(const f32x4_t*)(lbsh + chp*64 + i*32 + gq*8 + kh2*4);

  float vm[2];
#pragma unroll
  for (int j = 0; j < 2; ++j) {
    float v = -1e30f;
#pragma unroll
    for (int i = 0; i < 2; ++i)
#pragma unroll
      for (int gq = 0; gq < 4; ++gq)
#pragma unroll
        for (int t = 0; t < 4; ++t)
          v = fmaxf(v, acc[i][j][gq*4 + t] + bvv[i][gq][t]);
    v = fmaxf(v, __shfl_xor(v, 32));
    vm[j] = v;
  }
  if (chp == 0 && lane < 32) {
#pragma unroll
    for (int j = 0; j < 2; ++j) pmax[pxp*64 + j*32 + p] = vm[j];
  }
  __syncthreads();
  if (chp == 1 && lane < 32) {
#pragma unroll
    for (int j = 0; j < 2; ++j) {
      int px = pxp*64 + j*32 + p;
      float r = fmaxf(fmaxf(vm[j], pmax[px]), 0.0f);
      top1[(size_t)b*HW + (h0 + (px >> 4))*WW + (w0 + (px & 15))] = r;
      atomicAdd(&lhist[__float_as_uint(r) >> 21], 1u);
    }
  }
  __syncthreads();
  for (int i = tid; i < 1024; i += 512) {
    u32 cv = lhist[i];
    if (cv) atomicAdd(&gh[b*1024 + i], cv);
  }
}

// ---- select: prebuilt hist -> scan -> (cond. fine pass) -> compact -> sort ----
#define SNT 1024
__global__ void select_kernel(const float* __restrict__ top1, const u32* __restrict__ gh,
                              int* __restrict__ cand) {
  int img = blockIdx.x, tid = threadIdx.x;   // 1024 threads
  const float* v = top1 + (size_t)img * HW;
  const float4* v4 = (const float4*)v;
  __shared__ u32 hist[1024];
  __shared__ u64 keys[1024];
  __shared__ unsigned sG, scnt, sbin, sthr, snc;

  hist[tid] = gh[img*1024 + tid];
  __syncthreads();
  if (tid < 64) {
    int j = tid;
    unsigned s = 0;
#pragma unroll
    for (int i = 0; i < 16; ++i) s += hist[j*16 + i];
    unsigned a = s;
#pragma unroll
    for (int d = 1; d < 64; d <<= 1) { unsigned t = __shfl_down(a, d); if (j + d < 64) a += t; }
    unsigned above = a - s;
    if (above < TK && a >= TK) {
      unsigned cum = above;
      for (int i = 15; i >= 0; --i) {
        unsigned c = hist[j*16 + i];
        if (cum + c >= TK) { sG = cum; scnt = c; sbin = (unsigned)(j*16 + i); break; }
        cum += c;
      }
    }
    if (j == 0 && a < TK) { sG = 0; scnt = hist[0]; sbin = 0; }
  }
  __syncthreads();
  unsigned G = sG, cnt = scnt, binT = sbin;
  unsigned thr = binT << 21;
  if (G + cnt > 1024u) {
    __syncthreads();
    hist[tid] = 0u;
    __syncthreads();
    for (int i = tid; i < HW/4; i += SNT) {
      float4 f = v4[i];
      float fv[4] = {f.x, f.y, f.z, f.w};
#pragma unroll
      for (int c = 0; c < 4; ++c) {
        unsigned ub = __float_as_uint(fv[c]);
        if ((ub >> 21) == binT) atomicAdd(&hist[(ub >> 11) & 0x3FFu], 1u);
      }
    }
    __syncthreads();
    unsigned TK2 = TK - G;
    if (tid < 64) {
      int j = tid;
      unsigned s = 0;
#pragma unroll
      for (int i = 0; i < 16; ++i) s += hist[j*16 + i];
      unsigned a = s;
#pragma unroll
      for (int d = 1; d < 64; d <<= 1) { unsigned t = __shfl_down(a, d); if (j + d < 64) a += t; }
      unsigned above = a - s;
      if (above < TK2 && a >= TK2) {
        unsigned cum = above;
        for (int i = 15; i >= 0; --i) {
          unsigned c = hist[j*16 + i];
          if (cum + c >= TK2) { sthr = (binT << 21) | ((unsigned)(j*16 + i) << 11); break; }
          cum += c;
        }
      }
      if (j == 0 && a < TK2) sthr = binT << 21;
    }
    __syncthreads();
    thr = sthr;
  }
  if (tid == 0) snc = 0u;
  keys[tid] = 0ull;
  __syncthreads();
  for (int i = tid; i < HW/4; i += SNT) {
    float4 f = v4[i];
    float fv[4] = {f.x, f.y, f.z, f.w};
#pragma unroll
    for (int c = 0; c < 4; ++c) {
      unsigned ub = __float_as_uint(fv[c]);
      if (ub >= thr) {
        unsigned pp = atomicAdd(&snc, 1u);
        if (pp < 1024u) keys[pp] = ((u64)ub << 32) | (unsigned)(~(unsigned)(4*i + c));
      }
    }
  }
  for (unsigned kk = 2; kk <= 1024; kk <<= 1)
    for (unsigned j = kk >> 1; j > 0; j >>= 1) {
      __syncthreads();
      unsigned t = tid, ixj = t ^ j;
      if (ixj > t) {
        u64 a = keys[t], b = keys[ixj];
        bool desc = ((t & kk) == 0);
        if ((a < b) == desc) { keys[t] = b; keys[ixj] = a; }
      }
    }
  __syncthreads();
  if (tid < CAND) {
    u64 key = keys[tid];
    cand[img*CAND + tid] = (key == 0ull) ? -1 : (int)(~(unsigned)(key & 0xFFFFFFFFull));
  }
}

// ---- fp64 recompute at candidates (coalesced wT, LDS x-patch, parallel top3) ----
__global__ void refine_kernel(const float* __restrict__ x, const float* __restrict__ wT,
                              const float* __restrict__ cb, const float* __restrict__ gamma,
                              const float* __restrict__ beta, const float* __restrict__ mean,
                              const float* __restrict__ var, const int* __restrict__ cand,
                              u64* __restrict__ ckey,
                              float* __restrict__ c3v, float* __restrict__ c3i) {
#pragma clang fp contract(off)
  int slot = blockIdx.x, img = blockIdx.y;
  int c = threadIdx.x;                       // 128 threads = channels
  int sidx = cand[img*CAND + slot];
  if (sidx < 0) {
    if (c == 0) {
      ckey[img*CAND + slot] = 0ull;
      for (int j = 0; j < 3; ++j) { c3v[(img*CAND+slot)*3+j] = 0.f; c3i[(img*CAND+slot)*3+j] = 0.f; }
    }
    return;
  }
  int h = sidx / WW, wq = sidx % WW;
  const float* xb = x + (size_t)img * CIN * HW;

  __shared__ float xs[TAPS + 13];
  for (int t = c; t < TAPS; t += 128) {
    int cin = t / 49, r = t % 49;
    int kh = r / 7, kw = r % 7;
    int gh = h - 3 + kh, gw = wq - 3 + kw;
    float v = 0.0f;
    if (gh >= 0 && gh < HH && gw >= 0 && gw < WW) v = xb[cin*HW + gh*WW + gw];
    xs[t] = v;
  }
  __syncthreads();

  double acc = 0.0;
#pragma unroll 7
  for (int t = 0; t < TAPS; ++t)
    acc = fma((double)xs[t], (double)wT[t*COUT + c], acc);

  float y = (float)acc;
  y = y + cb[c];
  float s  = gamma[c] * (1.0f / sqrtf(var[c] + 1e-5f));
  float t1 = (y - mean[c]) * s;
  float z  = t1 + beta[c];
  z = fmaxf(z, 0.0f);

  __shared__ u64 zk[COUT];
  zk[c] = ((u64)__float_as_uint(z) << 32) | (unsigned)(127 - c);
  __syncthreads();
  if (c < 64) {
    u64 k0 = zk[c], k1 = zk[c + 64];
    int base = (img*CAND + slot)*3;
#pragma unroll
    for (int pick = 0; pick < 3; ++pick) {
      u64 m = (k0 > k1) ? k0 : k1;
#pragma unroll
      for (int d = 1; d < 64; d <<= 1) {
        u64 o = __shfl_xor((unsigned long long)m, d);
        if (o > m) m = o;
      }
      if (c == 0) {
        c3v[base + pick] = __uint_as_float((unsigned)(m >> 32));
        c3i[base + pick] = (float)(127 - (int)(m & 0xFFFFFFFFull));
        if (pick == 0)
          ckey[img*CAND + slot] = ((u64)(m >> 32) << 32) | (unsigned)(~(unsigned)sidx);
      }
      if (k0 == m) k0 = 0ull;
      if (k1 == m) k1 = 0ull;
    }
  }
}

// ---- final: sort 192 refined candidates, write all three outputs ----
__global__ void final_kernel(const u64* __restrict__ ckey, const int* __restrict__ cand,
                             const float* __restrict__ c3v, const float* __restrict__ c3i,
                             float* __restrict__ out) {
  int img = blockIdx.x, tid = threadIdx.x;   // 256 threads
  __shared__ u64 k[256];
  __shared__ int pay[256];
  k[tid]  = (tid < CAND) ? ckey[img*CAND + tid] : 0ull;
  pay[tid] = tid;
  for (unsigned kk = 2; kk <= 256; kk <<= 1)
    for (unsigned j = kk >> 1; j > 0; j >>= 1) {
      __syncthreads();
      unsigned i = tid, ixj = i ^ j;
      if (ixj > i) {
        u64 a = k[i], b = k[ixj];
        bool desc = ((i & kk) == 0);
        if ((a < b) == desc) {
          k[i] = b; k[ixj] = a;
          int p = pay[i]; pay[i] = pay[ixj]; pay[ixj] = p;
        }
      }
    }
  __syncthreads();
  if (tid < 128) {
    int slot = pay[tid];
    int sidx = cand[img*CAND + slot];
    out[12288 + img*128 + tid] = (float)sidx;
    int base = (img*CAND + slot)*3;
    for (int j = 0; j < 3; ++j) {
      out[(img*3 + j)*128 + tid]        = c3i[base + j];
      out[6144 + (img*3 + j)*128 + tid] = c3v[base + j];
    }
  }
}

extern "C" void kernel_launch(void* const* d_in, const int* in_sizes, int n_in,
                              void* d_out, int out_size, void* d_ws, size_t ws_size,
                              hipStream_t stream) {
  const float* x     = (const float*)d_in[0];
  const float* w     = (const float*)d_in[1];
  const float* cb    = (const float*)d_in[2];
  const float* gamma = (const float*)d_in[3];
  const float* beta  = (const float*)d_in[4];
  const float* mean  = (const float*)d_in[5];
  const float* var   = (const float*)d_in[6];
  float* out = (float*)d_out;
  char*  ws  = (char*)d_ws;

  unsigned short* Bg = (unsigned short*)(ws + WS_BG);
  float* bsh  = (float*)(ws + WS_BSH);
  float* top1 = (float*)(ws + WS_TOP1);
  int*   cidx = (int*)(ws + WS_CIDX);
  u64*   ck   = (u64*)(ws + WS_CKEY);
  float* c3v = (float*)(ws + WS_C3V);
  float* c3i = (float*)(ws + WS_C3I);
  float* wT  = (float*)(ws + WS_WT);
  u32* gh    = (u32*)(ws + WS_HIST);

  prep_kernel<<<COUT, 192, 0, stream>>>(w, cb, gamma, beta, mean, var, Bg, bsh, wT, gh);
  conv_mfma_kernel<<<dim3(WW/16, HH/16, BATCH), 512, LDS_CONV, stream>>>(x, Bg, bsh, top1, gh);
  select_kernel<<<BATCH, SNT, 0, stream>>>(top1, gh, cidx);
  refine_kernel<<<dim3(CAND, BATCH), COUT, 0, stream>>>(x, wT, cb, gamma, beta, mean, var,
                                                        cidx, ck, c3v, c3i);
  final_kernel<<<BATCH, 256, 0, stream>>>(ck, cidx, c3v, c3i, out);
}

// Round 25
// 90.942 us; speedup vs baseline: 1.0383x; 1.0132x over previous
//
#include <hip/hip_runtime.h>
#include <math.h>

#define BATCH 16
#define CIN   3
#define HH    224
#define WW    224
#define HW    (HH*WW)
#define COUT  128
#define TAPS  147
#define CAND  192
#define TK    192

typedef __attribute__((ext_vector_type(8))) _Float16 f16x8_t;
typedef decltype(__builtin_amdgcn_cvt_pkrtz(0.f, 0.f)) f16x2_t;
typedef __attribute__((ext_vector_type(4))) float f32x4_t;
typedef __attribute__((ext_vector_type(16))) float f32x16_t;
typedef __attribute__((ext_vector_type(4))) unsigned int u32x4_t;
typedef unsigned long long u64;
typedef unsigned int u32;

// W layout (global): [g 24][129 chunks of (ch,kw)] f16x8. Conv stages only g=0..21.
#define BSTG_CHUNKS (22*129)          // 2838 staged chunks
#define B_BYTES     (BSTG_CHUNKS*16u) // 45408
// x copies: stride 2192 B = 548 words == 4 mod 32 -> 8-bank spread, 2-way free
#define CPY_STRIDE 2192
#define CPY_BYTES  (8*CPY_STRIDE)     // 17536
// f32 staging tile: row stride 25 words (coprime 32 -> conflict-free copy-build reads)
#define XFSTR     25
// conv LDS layout
#define XF_OFF    (B_BYTES + CPY_BYTES)        // 62944
#define LBSH_OFF  (XF_OFF + 6656u)             // 69600 (xf 3*22*25*4=6600, pad 6656)
#define PMAX_OFF  (LBSH_OFF + 512u)            // 70112
#define LHIST_OFF (PMAX_OFF + 1024u)           // 71136
#define LDS_CONV  (LHIST_OFF + 4096u)          // 75232 -> 2 blocks/CU

// workspace layout (bytes); Bg buffer holds full 24-g table (prep writes all)
#define WS_BG    0u
#define WS_BSH   (WS_BG + (unsigned)(24*129*16))
#define WS_TOP1  (WS_BSH + 512u)
#define WS_CIDX  (WS_TOP1 + (unsigned)(BATCH*HW*4))
#define WS_CKEY  (WS_CIDX + (unsigned)(BATCH*CAND*4))
#define WS_C3V   (WS_CKEY + (unsigned)(BATCH*CAND*8))
#define WS_C3I   (WS_C3V + (unsigned)(BATCH*CAND*3*4))
#define WS_WT    (WS_C3I + (unsigned)(BATCH*CAND*3*4))
#define WS_HIST  (WS_WT + (unsigned)(TAPS*COUT*4))       // 16x1024 u32
#define ZERO_N   (BATCH*1024)

__device__ __forceinline__ void gload_lds16(const u32* g, u32* l) {
  __builtin_amdgcn_global_load_lds((const __attribute__((address_space(1))) u32*)g,
                                   (__attribute__((address_space(3))) u32*)l, 16, 0, 0);
}

// ---- prep: zero hist + fp16 folded weights + raw tap-major wT + BN shift ----
__global__ void prep_kernel(const float* __restrict__ w, const float* __restrict__ cb,
                            const float* __restrict__ gamma, const float* __restrict__ beta,
                            const float* __restrict__ mean, const float* __restrict__ var,
                            unsigned short* __restrict__ Bg, float* __restrict__ bsh,
                            float* __restrict__ wT, u32* __restrict__ gh) {
  int c = blockIdx.x;                 // 128
  int t = threadIdx.x;                // 192: g = t>>3 (0..23), kw = t&7
  int zi = c*192 + t;
  if (zi < ZERO_N) gh[zi] = 0u;
  float s = gamma[c] * (1.0f / sqrtf(var[c] + 1e-5f));
  int g = t >> 3, kw = t & 7;
  float wraw = 0.0f;
  if (g < 21 && kw < 7) {
    wraw = w[c*TAPS + g*7 + kw];
    wT[(g*7 + kw)*COUT + c] = wraw;
  }
  union { _Float16 h; unsigned short u; } cvt;
  cvt.h = (_Float16)(wraw * s);
  Bg[((g*129 + c)*8) + kw] = cvt.u;
  if (t == 0) bsh[c] = (cb[c] - mean[c]) * s + beta[c];
}

// ---- main pass: conv+BN+ReLU -> channel max + coarse hist ----
// 2 sub-tiles (16x16) per block: W staged once, fixed costs amortized.
__global__ __launch_bounds__(512, 4)
void conv_mfma_kernel(const float* __restrict__ x, const unsigned short* __restrict__ Bg,
                      const float* __restrict__ bsh, float* __restrict__ top1,
                      u32* __restrict__ gh) {
  extern __shared__ char smem[];
  char* xcop = smem + B_BYTES;
  float* xf   = (float*)(smem + XF_OFF);
  float* lbsh = (float*)(smem + LBSH_OFF);
  float* pmax = (float*)(smem + PMAX_OFF);
  u32* lhist  = (u32*)(smem + LHIST_OFF);

  int tid = threadIdx.x;
  int lane = tid & 63, wv = tid >> 6;
  int p = lane & 31, kh2 = lane >> 5;
  int chp = wv & 1, pxp = wv >> 1;
  int b = blockIdx.z, w0 = blockIdx.x*16, h0 = blockIdx.y*32;
  const float* xb = x + (size_t)b * CIN * HW;
  const u32* Bg32 = (const u32*)Bg;

  // stage W g=0..21 (async, 2838 chunks) -- once per block (2 tiles)
#pragma unroll
  for (int k = 0; k < 6; ++k) {
    int idx = tid + k*512;
    if (idx < BSTG_CHUNKS) gload_lds16(Bg32 + idx*4, (u32*)smem + idx*4);
  }
  // stage xf for sub-tile 0 (coalesced; dest stride 25)
  for (int i = tid; i < CIN*22*24; i += 512) {
    int cin = i / (22*24);
    int rem = i % (22*24);
    int r = rem / 24, col = rem % 24;
    int gh2 = h0 + r - 3, gw = w0 + col - 3;
    float v = 0.0f;
    if (gh2 >= 0 && gh2 < HH && gw >= 0 && gw < WW) v = xb[cin*HW + gh2*WW + gw];
    xf[(cin*22 + r)*XFSTR + col] = v;
  }
  if (tid < COUT) lbsh[tid] = bsh[tid];
  for (int i = tid; i < 1024; i += 512) lhist[i] = 0u;

  __syncthreads();   // W + xf(0) + lhist ready

  const f16x8_t* B8 = (const f16x8_t*)smem;
  int lane_base = (p & 7)*CPY_STRIDE + ((p >> 3) & 1)*16;
  const char* xl = xcop + lane_base;
  int prow = p >> 4;

#pragma unroll
  for (int jt = 0; jt < 2; ++jt) {
    int h0j = h0 + jt*16;
    if (jt == 1) {
      // stage xf for sub-tile 1 (all waves past copy-build(0): safe overwrite)
      for (int i = tid; i < CIN*22*24; i += 512) {
        int cin = i / (22*24);
        int rem = i % (22*24);
        int r = rem / 24, col = rem % 24;
        int gh2 = h0j + r - 3, gw = w0 + col - 3;
        float v = 0.0f;
        if (gh2 >= 0 && gh2 < HH && gw >= 0 && gw < WW) v = xb[cin*HW + gh2*WW + gw];
        xf[(cin*22 + r)*XFSTR + col] = v;
      }
      __syncthreads();   // xf(1) visible
    }

    // build 8 shifted fp16 copies LDS->LDS (all waves past K-loop(jt-1): safe)
    for (int c = tid; c < 8*132; c += 512) {
      int s   = c / 132;
      int rem = c % 132;
      int cin = rem / 44;
      int rm2 = rem % 44;
      int r   = rm2 >> 1, cj = rm2 & 1;
      const float* src = xf + (cin*22 + r)*XFSTR + 8*cj + s;
      float xv[8];
#pragma unroll
      for (int j = 0; j < 8; ++j) xv[j] = src[j];
      union { f16x2_t pk[4]; u32x4_t v; } P;
#pragma unroll
      for (int j = 0; j < 4; ++j)
        P.pk[j] = __builtin_amdgcn_cvt_pkrtz(xv[2*j], xv[2*j+1]);
      *(u32x4_t*)(xcop + s*CPY_STRIDE + (cin*22 + r)*32 + cj*16) = P.v;
    }

    __syncthreads();   // xcop ready

    f32x16_t acc[2][2];
#pragma unroll
    for (int i = 0; i < 2; ++i)
#pragma unroll
      for (int j = 0; j < 2; ++j)
#pragma unroll
        for (int r = 0; r < 16; ++r) acc[i][j][r] = 0.0f;

    // 11 K-iterations cover g=0..21 (g=21 is the single zero-pad octet)
#pragma unroll
    for (int kf = 0; kf < 11; ++kf) {
      int g = kf*2 + kh2;
      f16x8_t Wn[2];
#pragma unroll
      for (int i = 0; i < 2; ++i)
        Wn[i] = B8[g*129 + chp*64 + i*32 + p];
      int cin = (g*37) >> 8;
      int kh = g - cin*7;
      int rowb = (g < 21) ? (cin*22 + kh) : 0;   // g=21 clamped (W=0 there)
#pragma unroll
      for (int j = 0; j < 2; ++j) {
        int pxrow = pxp*4 + j*2 + prow;
        f16x8_t Av = *(const f16x8_t*)(xl + (rowb + pxrow)*32);
#pragma unroll
        for (int i = 0; i < 2; ++i)
          acc[i][j] = __builtin_amdgcn_mfma_f32_32x32x16_f16(Wn[i], Av, acc[i][j], 0, 0, 0);
      }
    }

    // epilogue: +bias, 32 in-lane fmax, 1 shfl, chp combine, hist
    f32x4_t bvv[2][4];
#pragma unroll
    for (int i = 0; i < 2; ++i)
#pragma unroll
      for (int gq = 0; gq < 4; ++gq)
        bvv[i][gq] = *(const f32x4_t*)(lbsh + chp*64 + i*32 + gq*8 + kh2*4);

    float vm[2];
#pragma unroll
    for (int j = 0; j < 2; ++j) {
      float v = -1e30f;
#pragma unroll
      for (int i = 0; i < 2; ++i)
#pragma unroll
        for (int gq = 0; gq < 4; ++gq)
#pragma unroll
          for (int t = 0; t < 4; ++t)
            v = fmaxf(v, acc[i][j][gq*4 + t] + bvv[i][gq][t]);
      v = fmaxf(v, __shfl_xor(v, 32));
      vm[j] = v;
    }
    if (chp == 0 && lane < 32) {
#pragma unroll
      for (int j = 0; j < 2; ++j) pmax[pxp*64 + j*32 + p] = vm[j];
    }
    __syncthreads();
    if (chp == 1 && lane < 32) {
#pragma unroll
      for (int j = 0; j < 2; ++j) {
        int px = pxp*64 + j*32 + p;
        float r = fmaxf(fmaxf(vm[j], pmax[px]), 0.0f);
        top1[(size_t)b*HW + (h0j + (px >> 4))*WW + (w0 + (px & 15))] = r;
        atomicAdd(&lhist[__float_as_uint(r) >> 21], 1u);
      }
    }
    __syncthreads();   // lhist adds done; safe to restage xf / rebuild xcop
  }

  // merge local hist -> global (once per block)
  for (int i = tid; i < 1024; i += 512) {
    u32 cv = lhist[i];
    if (cv) atomicAdd(&gh[b*1024 + i], cv);
  }
}

// ---- select: prebuilt hist -> scan -> (cond. fine pass) -> compact -> sort ----
#define SNT 1024
__global__ void select_kernel(const float* __restrict__ top1, const u32* __restrict__ gh,
                              int* __restrict__ cand) {
  int img = blockIdx.x, tid = threadIdx.x;   // 1024 threads
  const float* v = top1 + (size_t)img * HW;
  const float4* v4 = (const float4*)v;
  __shared__ u32 hist[1024];
  __shared__ u64 keys[1024];
  __shared__ unsigned sG, scnt, sbin, sthr, snc;

  hist[tid] = gh[img*1024 + tid];
  __syncthreads();
  if (tid < 64) {
    int j = tid;
    unsigned s = 0;
#pragma unroll
    for (int i = 0; i < 16; ++i) s += hist[j*16 + i];
    unsigned a = s;
#pragma unroll
    for (int d = 1; d < 64; d <<= 1) { unsigned t = __shfl_down(a, d); if (j + d < 64) a += t; }
    unsigned above = a - s;
    if (above < TK && a >= TK) {
      unsigned cum = above;
      for (int i = 15; i >= 0; --i) {
        unsigned c = hist[j*16 + i];
        if (cum + c >= TK) { sG = cum; scnt = c; sbin = (unsigned)(j*16 + i); break; }
        cum += c;
      }
    }
    if (j == 0 && a < TK) { sG = 0; scnt = hist[0]; sbin = 0; }
  }
  __syncthreads();
  unsigned G = sG, cnt = scnt, binT = sbin;
  unsigned thr = binT << 21;
  if (G + cnt > 1024u) {
    __syncthreads();
    hist[tid] = 0u;
    __syncthreads();
    for (int i = tid; i < HW/4; i += SNT) {
      float4 f = v4[i];
      float fv[4] = {f.x, f.y, f.z, f.w};
#pragma unroll
      for (int c = 0; c < 4; ++c) {
        unsigned ub = __float_as_uint(fv[c]);
        if ((ub >> 21) == binT) atomicAdd(&hist[(ub >> 11) & 0x3FFu], 1u);
      }
    }
    __syncthreads();
    unsigned TK2 = TK - G;
    if (tid < 64) {
      int j = tid;
      unsigned s = 0;
#pragma unroll
      for (int i = 0; i < 16; ++i) s += hist[j*16 + i];
      unsigned a = s;
#pragma unroll
      for (int d = 1; d < 64; d <<= 1) { unsigned t = __shfl_down(a, d); if (j + d < 64) a += t; }
      unsigned above = a - s;
      if (above < TK2 && a >= TK2) {
        unsigned cum = above;
        for (int i = 15; i >= 0; --i) {
          unsigned c = hist[j*16 + i];
          if (cum + c >= TK2) { sthr = (binT << 21) | ((unsigned)(j*16 + i) << 11); break; }
          cum += c;
        }
      }
      if (j == 0 && a < TK2) sthr = binT << 21;
    }
    __syncthreads();
    thr = sthr;
  }
  if (tid == 0) snc = 0u;
  keys[tid] = 0ull;
  __syncthreads();
  for (int i = tid; i < HW/4; i += SNT) {
    float4 f = v4[i];
    float fv[4] = {f.x, f.y, f.z, f.w};
#pragma unroll
    for (int c = 0; c < 4; ++c) {
      unsigned ub = __float_as_uint(fv[c]);
      if (ub >= thr) {
        unsigned pp = atomicAdd(&snc, 1u);
        if (pp < 1024u) keys[pp] = ((u64)ub << 32) | (unsigned)(~(unsigned)(4*i + c));
      }
    }
  }
  for (unsigned kk = 2; kk <= 1024; kk <<= 1)
    for (unsigned j = kk >> 1; j > 0; j >>= 1) {
      __syncthreads();
      unsigned t = tid, ixj = t ^ j;
      if (ixj > t) {
        u64 a = keys[t], b = keys[ixj];
        bool desc = ((t & kk) == 0);
        if ((a < b) == desc) { keys[t] = b; keys[ixj] = a; }
      }
    }
  __syncthreads();
  if (tid < CAND) {
    u64 key = keys[tid];
    cand[img*CAND + tid] = (key == 0ull) ? -1 : (int)(~(unsigned)(key & 0xFFFFFFFFull));
  }
}

// ---- fp64 recompute at candidates (coalesced wT, LDS x-patch, parallel top3) ----
__global__ void refine_kernel(const float* __restrict__ x, const float* __restrict__ wT,
                              const float* __restrict__ cb, const float* __restrict__ gamma,
                              const float* __restrict__ beta, const float* __restrict__ mean,
                              const float* __restrict__ var, const int* __restrict__ cand,
                              u64* __restrict__ ckey,
                              float* __restrict__ c3v, float* __restrict__ c3i) {
#pragma clang fp contract(off)
  int slot = blockIdx.x, img = blockIdx.y;
  int c = threadIdx.x;                       // 128 threads = channels
  int sidx = cand[img*CAND + slot];
  if (sidx < 0) {
    if (c == 0) {
      ckey[img*CAND + slot] = 0ull;
      for (int j = 0; j < 3; ++j) { c3v[(img*CAND+slot)*3+j] = 0.f; c3i[(img*CAND+slot)*3+j] = 0.f; }
    }
    return;
  }
  int h = sidx / WW, wq = sidx % WW;
  const float* xb = x + (size_t)img * CIN * HW;

  __shared__ float xs[TAPS + 13];
  for (int t = c; t < TAPS; t += 128) {
    int cin = t / 49, r = t % 49;
    int kh = r / 7, kw = r % 7;
    int gh = h - 3 + kh, gw = wq - 3 + kw;
    float v = 0.0f;
    if (gh >= 0 && gh < HH && gw >= 0 && gw < WW) v = xb[cin*HW + gh*WW + gw];
    xs[t] = v;
  }
  __syncthreads();

  double acc = 0.0;
#pragma unroll 7
  for (int t = 0; t < TAPS; ++t)
    acc = fma((double)xs[t], (double)wT[t*COUT + c], acc);

  float y = (float)acc;
  y = y + cb[c];
  float s  = gamma[c] * (1.0f / sqrtf(var[c] + 1e-5f));
  float t1 = (y - mean[c]) * s;
  float z  = t1 + beta[c];
  z = fmaxf(z, 0.0f);

  __shared__ u64 zk[COUT];
  zk[c] = ((u64)__float_as_uint(z) << 32) | (unsigned)(127 - c);
  __syncthreads();
  if (c < 64) {
    u64 k0 = zk[c], k1 = zk[c + 64];
    int base = (img*CAND + slot)*3;
#pragma unroll
    for (int pick = 0; pick < 3; ++pick) {
      u64 m = (k0 > k1) ? k0 : k1;
#pragma unroll
      for (int d = 1; d < 64; d <<= 1) {
        u64 o = __shfl_xor((unsigned long long)m, d);
        if (o > m) m = o;
      }
      if (c == 0) {
        c3v[base + pick] = __uint_as_float((unsigned)(m >> 32));
        c3i[base + pick] = (float)(127 - (int)(m & 0xFFFFFFFFull));
        if (pick == 0)
          ckey[img*CAND + slot] = ((u64)(m >> 32) << 32) | (unsigned)(~(unsigned)sidx);
      }
      if (k0 == m) k0 = 0ull;
      if (k1 == m) k1 = 0ull;
    }
  }
}

// ---- final: sort 192 refined candidates, write all three outputs ----
__global__ void final_kernel(const u64* __restrict__ ckey, const int* __restrict__ cand,
                             const float* __restrict__ c3v, const float* __restrict__ c3i,
                             float* __restrict__ out) {
  int img = blockIdx.x, tid = threadIdx.x;   // 256 threads
  __shared__ u64 k[256];
  __shared__ int pay[256];
  k[tid]  = (tid < CAND) ? ckey[img*CAND + tid] : 0ull;
  pay[tid] = tid;
  for (unsigned kk = 2; kk <= 256; kk <<= 1)
    for (unsigned j = kk >> 1; j > 0; j >>= 1) {
      __syncthreads();
      unsigned i = tid, ixj = i ^ j;
      if (ixj > i) {
        u64 a = k[i], b = k[ixj];
        bool desc = ((i & kk) == 0);
        if ((a < b) == desc) {
          k[i] = b; k[ixj] = a;
          int p = pay[i]; pay[i] = pay[ixj]; pay[ixj] = p;
        }
      }
    }
  __syncthreads();
  if (tid < 128) {
    int slot = pay[tid];
    int sidx = cand[img*CAND + slot];
    out[12288 + img*128 + tid] = (float)sidx;
    int base = (img*CAND + slot)*3;
    for (int j = 0; j < 3; ++j) {
      out[(img*3 + j)*128 + tid]        = c3i[base + j];
      out[6144 + (img*3 + j)*128 + tid] = c3v[base + j];
    }
  }
}

extern "C" void kernel_launch(void* const* d_in, const int* in_sizes, int n_in,
                              void* d_out, int out_size, void* d_ws, size_t ws_size,
                              hipStream_t stream) {
  const float* x     = (const float*)d_in[0];
  const float* w     = (const float*)d_in[1];
  const float* cb    = (const float*)d_in[2];
  const float* gamma = (const float*)d_in[3];
  const float* beta  = (const float*)d_in[4];
  const float* mean  = (const float*)d_in[5];
  const float* var   = (const float*)d_in[6];
  float* out = (float*)d_out;
  char*  ws  = (char*)d_ws;

  unsigned short* Bg = (unsigned short*)(ws + WS_BG);
  float* bsh  = (float*)(ws + WS_BSH);
  float* top1 = (float*)(ws + WS_TOP1);
  int*   cidx = (int*)(ws + WS_CIDX);
  u64*   ck   = (u64*)(ws + WS_CKEY);
  float* c3v = (float*)(ws + WS_C3V);
  float* c3i = (float*)(ws + WS_C3I);
  float* wT  = (float*)(ws + WS_WT);
  u32* gh    = (u32*)(ws + WS_HIST);

  prep_kernel<<<COUT, 192, 0, stream>>>(w, cb, gamma, beta, mean, var, Bg, bsh, wT, gh);
  conv_mfma_kernel<<<dim3(WW/16, HH/32, BATCH), 512, LDS_CONV, stream>>>(x, Bg, bsh, top1, gh);
  select_kernel<<<BATCH, SNT, 0, stream>>>(top1, gh, cidx);
  refine_kernel<<<dim3(CAND, BATCH), COUT, 0, stream>>>(x, wT, cb, gamma, beta, mean, var,
                                                        cidx, ck, c3v, c3i);
  final_kernel<<<BATCH, 256, 0, stream>>>(ck, cidx, c3v, c3i, out);
}